// Round 4
// 613.207 us; speedup vs baseline: 1.0813x; 1.0813x over previous
//
#include <hip/hip_runtime.h>
#include <hip/hip_bf16.h>
#include <stdint.h>

typedef __attribute__((ext_vector_type(8))) short short8;
typedef __attribute__((ext_vector_type(4))) float floatx4;

#define GLOAD_LDS16(gptr, lptr)                                                     \
  __builtin_amdgcn_global_load_lds(                                                 \
      (const __attribute__((address_space(1))) void*)(gptr),                        \
      (__attribute__((address_space(3))) void*)(lptr), 16, 0, 0)

#define FENCE() asm volatile("" ::: "memory")
#define BARRIER() do { FENCE(); __builtin_amdgcn_s_barrier(); FENCE(); } while (0)
#define WAIT_LGKM0() do { asm volatile("s_waitcnt lgkmcnt(0)" ::: "memory"); \
                          __builtin_amdgcn_sched_barrier(0); } while (0)

__device__ inline void fwht16(float v[16]) {
#pragma unroll
    for (int s = 0; s < 4; ++s) {
        const int h = 1 << s;
#pragma unroll
        for (int k = 0; k < 16; k += 2 * h)
#pragma unroll
            for (int j = 0; j < h; ++j) {
                float a = v[k + j], b = v[k + j + h];
                v[k + j] = a + b;
                v[k + j + h] = a - b;
            }
    }
}

// ---------------------------------------------------------------------------
// Kernel 1: W_eff[o][i] = Wscale * D4_CB[Qidxs[o][i/4]][i%4] + sum_r A[o][r]*B[r][i]
// grid (16 i-tiles of 256, 64 o-tiles of 64), block 256.  (unchanged)
// ---------------------------------------------------------------------------
__global__ __launch_bounds__(256) void decode_weff(
    const int* __restrict__ Qidxs, const float* __restrict__ D4_CB,
    const float* __restrict__ Wscale_p, const float* __restrict__ A,
    const float* __restrict__ B, __hip_bfloat16* __restrict__ W_eff)
{
    __shared__ __align__(16) float As[64 * 64];   // A[oBase+oo][r]
    __shared__ __align__(16) float CB[256 * 4];
    const int t = threadIdx.x;
    const int oBase = blockIdx.y * 64;
    const int iBase = blockIdx.x * 256;

    const float4* A4 = (const float4*)(A + (long)oBase * 64);
    float4* As4 = (float4*)As;
#pragma unroll
    for (int u = 0; u < 4; ++u) As4[t + u * 256] = A4[t + u * 256];
    ((float4*)CB)[t] = ((const float4*)D4_CB)[t];
    __syncthreads();

    const float wscale = Wscale_p[0];
    const int i = iBase + t;
    float bcol[64];
#pragma unroll
    for (int r = 0; r < 64; ++r) bcol[r] = B[r * 4096 + i];

    const int g = i >> 2;
    const int sub = i & 3;

    for (int oo = 0; oo < 64; ++oo) {
        const int o = oBase + oo;
        const float4* arow = (const float4*)&As[oo * 64];
        float acc = 0.f;
#pragma unroll
        for (int r4 = 0; r4 < 16; ++r4) {
            float4 a4 = arow[r4];
            acc += a4.x * bcol[4 * r4 + 0] + a4.y * bcol[4 * r4 + 1] +
                   a4.z * bcol[4 * r4 + 2] + a4.w * bcol[4 * r4 + 3];
        }
        const int q = Qidxs[(long)o * 1024 + g];
        const float w = wscale * CB[q * 4 + sub] + acc;
        W_eff[(long)o * 4096 + i] = __float2bfloat16(w);
    }
}

// ---------------------------------------------------------------------------
// Kernel 2: per row: x/scaleWH*SU -> FWHT(4096) -> *1/64 -> bf16  (unchanged)
// ---------------------------------------------------------------------------
__global__ __launch_bounds__(256) void fwht_in_kernel(
    const float* __restrict__ x, const float* __restrict__ SU,
    const float* __restrict__ sWH, __hip_bfloat16* __restrict__ xh)
{
    __shared__ float row[4096 + 256];
    const int t = threadIdx.x;
    const long base = (long)blockIdx.x * 4096;
    float v[16];

#pragma unroll
    for (int u = 0; u < 16; ++u) {
        int e = u * 256 + t;
        v[u] = x[base + e] / sWH[e] * SU[e];
    }
    fwht16(v);
#pragma unroll
    for (int u = 0; u < 16; ++u) {
        int e = u * 256 + t;
        row[e + (e >> 4)] = v[u];
    }
    __syncthreads();

    const int lo = t & 15, hi = t >> 4;
#pragma unroll
    for (int u = 0; u < 16; ++u) v[u] = row[hi * 272 + u * 17 + lo];
    fwht16(v);
#pragma unroll
    for (int u = 0; u < 16; ++u) row[hi * 272 + u * 17 + lo] = v[u];
    __syncthreads();

#pragma unroll
    for (int u = 0; u < 16; ++u) v[u] = row[t * 17 + u];
    fwht16(v);

    short8 o0, o1;
#pragma unroll
    for (int u = 0; u < 8; ++u) {
        __hip_bfloat16 b = __float2bfloat16(v[u] * 0.015625f);
        o0[u] = *(short*)&b;
    }
#pragma unroll
    for (int u = 0; u < 8; ++u) {
        __hip_bfloat16 b = __float2bfloat16(v[8 + u] * 0.015625f);
        o1[u] = *(short*)&b;
    }
    *(short8*)(xh + base + t * 16) = o0;
    *(short8*)(xh + base + t * 16 + 8) = o1;
}

// ---------------------------------------------------------------------------
// Kernel 3: z[m][n] = sum_k xh[m][k] * W_eff[n][k]   (bf16 in, bf16 out)
// 256x256 tile, BK=64, 512 thr (2x4 waves, 128x64 out/wave), 8-phase schedule
// (T2 XOR swizzle + T3/T4 counted vmcnt + T5 setprio).
// LDS: 2 x (256x64) bf16 per matrix = 128 KiB, double-buffered by K-tile.
// Swizzle: LDS slot (row, c) holds global 16B chunk c ^ (row&7); inverse
// applied on the per-lane global source (global_load_lds dest stays linear),
// forward applied on ds_read addresses -> conflict-free b128 reads.
// Stage stream per tile t: p0:Ah1(t+1) p1:Bh1(t+1) p2:Bh0(t+2) p3:Ah0(t+2).
// Safety: B-buf[t&1] dead after phase-1 barrier, A-buf[t&1] dead after
// phase-2 barrier, so the t+2 (same-parity) stages in p2/p3 cannot race.
// vmcnt(4) at tile end proves all of tile t+1 resident (newest 4 loads are
// the t+2 halves).
// ---------------------------------------------------------------------------
__global__ __launch_bounds__(512, 2) void gemm_bt(
    const __hip_bfloat16* __restrict__ xh,
    const __hip_bfloat16* __restrict__ wf,
    __hip_bfloat16* __restrict__ z)
{
    __shared__ __align__(16) __hip_bfloat16 sA[2][256 * 64];
    __shared__ __align__(16) __hip_bfloat16 sB[2][256 * 64];

    const int t = threadIdx.x;
    const int lane = t & 63;
    const int wv = t >> 6;            // 0..7
    const int wm = wv >> 2;           // 0..1  (M half of tile)
    const int wn = wv & 3;            // 0..3  (N quarter of tile)
    const long mBase = (long)blockIdx.y * 256;
    const long nBase = (long)blockIdx.x * 256;

    // --- staging: thread t covers rows (t>>3), LDS slot chunk (t&7);
    //     global chunk = slot ^ (row&7)  (pre-swizzled source, linear dest)
    const int grow = t >> 3;                       // 0..63 within an issue
    const int gcol = ((t & 7) ^ (grow & 7)) * 8;   // element offset in row
    const __hip_bfloat16* gA = xh + (mBase + grow) * 4096 + gcol;
    const __hip_bfloat16* gB = wf + (nBase + grow) * 4096 + gcol;
    const int lrow = wv * 8;          // wave's row base within an issue

    // --- fragment read offsets: frag row = base+fr, chunk q = kh*4+(lane>>4),
    //     LDS slot = q ^ (fr&7)
    const int fr = lane & 15;
    const int c2 = lane >> 4;                      // 0..3
    const int slot0 = ((c2 ^ (fr & 7)) * 8);       // kh=0 (elements); kh=1: ^32

    floatx4 acc[8][4] = {};
    short8 afr[4][2];   // current M-half fragments  (m x kh)
    short8 bfr[4][2];   // all 4 N fragments         (n x kh)

    // issue one 128-row half-tile (2 x global_load_lds dwordx4)
    auto stage = [&](int buf, int isA, int halfRow, int kt) {
        const __hip_bfloat16* g =
            (isA ? gA : gB) + (long)halfRow * 4096 + (long)kt * 64;
        __hip_bfloat16* l =
            (isA ? &sA[buf][0] : &sB[buf][0]) + (halfRow + lrow) * 64;
        GLOAD_LDS16(g, l);
        GLOAD_LDS16(g + 64L * 4096, l + 64 * 64);
    };
    auto ldA = [&](int buf, int mhalf) {   // 8 ds_read_b128
        const __hip_bfloat16* base =
            &sA[buf][0] + (wm * 128 + mhalf * 64 + fr) * 64;
#pragma unroll
        for (int m = 0; m < 4; ++m) {
            afr[m][0] = *(const short8*)(base + m * 16 * 64 + slot0);
            afr[m][1] = *(const short8*)(base + m * 16 * 64 + (slot0 ^ 32));
        }
    };
    auto ldB2 = [&](int buf, int npair) {  // 4 ds_read_b128
        const __hip_bfloat16* base =
            &sB[buf][0] + (wn * 64 + npair * 32 + fr) * 64;
#pragma unroll
        for (int n = 0; n < 2; ++n) {
            bfr[npair * 2 + n][0] = *(const short8*)(base + n * 16 * 64 + slot0);
            bfr[npair * 2 + n][1] = *(const short8*)(base + n * 16 * 64 + (slot0 ^ 32));
        }
    };
    auto mma16 = [&](int mh, int np) {     // 16 MFMA: one C-quadrant x K=64
#pragma unroll
        for (int m = 0; m < 4; ++m)
#pragma unroll
            for (int n = 0; n < 2; ++n)
#pragma unroll
                for (int kh = 0; kh < 2; ++kh)
                    acc[mh * 4 + m][np * 2 + n] =
                        __builtin_amdgcn_mfma_f32_16x16x32_bf16(
                            afr[m][kh], bfr[np * 2 + n][kh],
                            acc[mh * 4 + m][np * 2 + n], 0, 0, 0);
    };

    // --- prologue: tile0 fully + {Bh0,Ah0} of tile1; keep 2 halves in flight
    stage(0, 1, 0,   0);   // Ah0(0)
    stage(0, 1, 128, 0);   // Ah1(0)
    stage(0, 0, 0,   0);   // Bh0(0)
    stage(0, 0, 128, 0);   // Bh1(0)
    stage(1, 0, 0,   1);   // Bh0(1)
    stage(1, 1, 0,   1);   // Ah0(1)
    asm volatile("s_waitcnt vmcnt(4)" ::: "memory");
    BARRIER();

    for (int kt = 0; kt < 64; ++kt) {
        const int cur = kt & 1;

        // ---- phase 0: A m0-3 + B n0-1 (12 reads) | stage Ah1(t+1)
        ldA(cur, 0);
        ldB2(cur, 0);
        if (kt + 1 < 64) stage(cur ^ 1, 1, 128, kt + 1);
        asm volatile("s_waitcnt lgkmcnt(8)" ::: "memory");
        BARRIER();
        WAIT_LGKM0();
        __builtin_amdgcn_s_setprio(1);
        mma16(0, 0);
        __builtin_amdgcn_s_setprio(0);
        BARRIER();

        // ---- phase 1: B n2-3 (4 reads) | stage Bh1(t+1)
        ldB2(cur, 1);
        if (kt + 1 < 64) stage(cur ^ 1, 0, 128, kt + 1);
        BARRIER();
        WAIT_LGKM0();
        __builtin_amdgcn_s_setprio(1);
        mma16(0, 1);
        __builtin_amdgcn_s_setprio(0);
        BARRIER();

        // ---- phase 2: A m4-7 (8 reads) | stage Bh0(t+2)  (B-buf dead)
        ldA(cur, 1);
        if (kt + 2 < 64) stage(cur, 0, 0, kt + 2);
        BARRIER();
        WAIT_LGKM0();
        __builtin_amdgcn_s_setprio(1);
        mma16(1, 0);
        __builtin_amdgcn_s_setprio(0);
        BARRIER();

        // ---- phase 3: no reads | stage Ah0(t+2)  (A-buf dead)
        if (kt + 2 < 64) stage(cur, 1, 0, kt + 2);
        BARRIER();
        WAIT_LGKM0();
        __builtin_amdgcn_s_setprio(1);
        mma16(1, 1);
        __builtin_amdgcn_s_setprio(0);
        if (kt < 62) asm volatile("s_waitcnt vmcnt(4)" ::: "memory");
        else         asm volatile("s_waitcnt vmcnt(0)" ::: "memory");
        BARRIER();
    }

    // ---- epilogue: C/D layout col=lane&15, row=(lane>>4)*4+reg
    const int q4 = c2 * 4;
#pragma unroll
    for (int m = 0; m < 8; ++m)
#pragma unroll
        for (int n = 0; n < 4; ++n)
#pragma unroll
            for (int r = 0; r < 4; ++r) {
                const long row = mBase + wm * 128 + m * 16 + q4 + r;
                const long col = nBase + wn * 64 + n * 16 + fr;
                z[row * 4096 + col] = __float2bfloat16(acc[m][n][r]);
            }
}

// ---------------------------------------------------------------------------
// Kernel 4: per row: bf16 z -> FWHT(4096) -> *SV/64 -> fp32 out  (unchanged)
// ---------------------------------------------------------------------------
__global__ __launch_bounds__(256) void fwht_out_kernel(
    const __hip_bfloat16* __restrict__ z, const float* __restrict__ SV,
    float* __restrict__ out)
{
    __shared__ float row[4096 + 256];
    const int t = threadIdx.x;
    const long base = (long)blockIdx.x * 4096;
    float v[16];

#pragma unroll
    for (int u = 0; u < 16; ++u) {
        int e = u * 256 + t;
        v[u] = __bfloat162float(z[base + e]);
    }
    fwht16(v);
#pragma unroll
    for (int u = 0; u < 16; ++u) {
        int e = u * 256 + t;
        row[e + (e >> 4)] = v[u];
    }
    __syncthreads();

    const int lo = t & 15, hi = t >> 4;
#pragma unroll
    for (int u = 0; u < 16; ++u) v[u] = row[hi * 272 + u * 17 + lo];
    fwht16(v);
#pragma unroll
    for (int u = 0; u < 16; ++u) row[hi * 272 + u * 17 + lo] = v[u];
    __syncthreads();

#pragma unroll
    for (int u = 0; u < 16; ++u) v[u] = row[t * 17 + u];
    fwht16(v);

    const float4* svv = (const float4*)(SV + t * 16);
    float4* ov = (float4*)(out + base + t * 16);
#pragma unroll
    for (int c = 0; c < 4; ++c) {
        float4 s = svv[c];
        float4 f;
        f.x = v[4 * c + 0] * s.x * 0.015625f;
        f.y = v[4 * c + 1] * s.y * 0.015625f;
        f.z = v[4 * c + 2] * s.z * 0.015625f;
        f.w = v[4 * c + 3] * s.w * 0.015625f;
        ov[c] = f;
    }
}

// ---------------------------------------------------------------------------
extern "C" void kernel_launch(void* const* d_in, const int* in_sizes, int n_in,
                              void* d_out, int out_size, void* d_ws, size_t ws_size,
                              hipStream_t stream)
{
    const float* input  = (const float*)d_in[0];
    const int*   Qidxs  = (const int*)d_in[1];
    const float* D4_CB  = (const float*)d_in[2];
    const float* SU     = (const float*)d_in[3];
    const float* SV     = (const float*)d_in[4];
    const float* Wscale = (const float*)d_in[5];
    const float* A      = (const float*)d_in[6];
    const float* B      = (const float*)d_in[7];
    const float* sWH    = (const float*)d_in[8];
    float* out = (float*)d_out;

    char* ws = (char*)d_ws;
    __hip_bfloat16* weff = (__hip_bfloat16*)ws;                               // 32 MiB
    __hip_bfloat16* xh   = (__hip_bfloat16*)(ws + (32L << 20));               // 64 MiB
    __hip_bfloat16* zbuf = (__hip_bfloat16*)(ws + (32L << 20) + (64L << 20)); // 64 MiB

    decode_weff<<<dim3(16, 64), 256, 0, stream>>>(Qidxs, D4_CB, Wscale, A, B, weff);
    fwht_in_kernel<<<8192, 256, 0, stream>>>(input, SU, sWH, xh);
    gemm_bt<<<dim3(16, 32), 512, 0, stream>>>(xh, weff, zbuf);
    fwht_out_kernel<<<8192, 256, 0, stream>>>(zbuf, SV, out);
}